// Round 1
// baseline (838.479 us; speedup 1.0000x reference)
//
#include <hip/hip_runtime.h>
#include <hip/hip_bf16.h>

typedef __bf16 bf16x8 __attribute__((ext_vector_type(8)));
typedef float f32x4 __attribute__((ext_vector_type(4)));
typedef float f32x16 __attribute__((ext_vector_type(16)));

#define NF 8192      // full node count
#define KSPLIT 8

static __device__ __forceinline__ unsigned short f2bf(float f) {
  __hip_bfloat16 h = __float2bfloat16(f);
  return __builtin_bit_cast(unsigned short, h);
}
static __device__ __forceinline__ float bf2f(unsigned short u) {
  __hip_bfloat16 h = __builtin_bit_cast(__hip_bfloat16, u);
  return __bfloat162float(h);
}
static __device__ __forceinline__ bf16x8 ldb(const unsigned short* p) {
  return *reinterpret_cast<const bf16x8*>(p);
}

// ---------------- S f32 -> bf16 ----------------
__global__ void k_cvt(const float* __restrict__ s, unsigned short* __restrict__ d, int n4) {
  int i = blockIdx.x * blockDim.x + threadIdx.x;
  int stride = gridDim.x * blockDim.x;
  for (; i < n4; i += stride) {
    float4 v = reinterpret_cast<const float4*>(s)[i];
    ushort4 o;
    o.x = f2bf(v.x); o.y = f2bf(v.y); o.z = f2bf(v.z); o.w = f2bf(v.w);
    reinterpret_cast<ushort4*>(d)[i] = o;
  }
}

// ---------------- x -> hi/lo bf16 planes (layer-1 z0, layout [16][8192]) ----------------
__global__ void k_split(const float* __restrict__ x, unsigned short* __restrict__ hi,
                        unsigned short* __restrict__ lo, int n) {
  int i = blockIdx.x * blockDim.x + threadIdx.x;
  if (i < n) {
    float v = x[i];
    unsigned short h = f2bf(v);
    hi[i] = h;
    lo[i] = f2bf(v - bf2f(h));
  }
}

// ---------------- hop, C=16 (layer 1): part[by][c][n] = sum_m Z^T[c][m] * S[n][m] ----------------
// Z planes [16][8192]; S [8192][8192] bf16; 16x16x32 MFMA, transposed-output formulation.
__global__ __launch_bounds__(256) void k_hop16(const unsigned short* __restrict__ S,
                                               const unsigned short* __restrict__ zhi,
                                               const unsigned short* __restrict__ zlo,
                                               float* __restrict__ part, int ktot) {
  const int kc = ktot / KSPLIT;
  const int k0 = blockIdx.y * kc;
  const int tid = threadIdx.x, l = tid & 63, w = tid >> 6;
  const int lk = (l >> 4) * 8;          // k offset within fragment
  const int l15 = l & 15;
  const int nb = blockIdx.x * 128 + w * 32;
  const unsigned short* pAh = zhi + (size_t)l15 * NF + k0 + lk;
  const unsigned short* pAl = zlo + (size_t)l15 * NF + k0 + lk;
  const unsigned short* pB0 = S + (size_t)(nb + l15) * NF + k0 + lk;
  const unsigned short* pB1 = S + (size_t)(nb + 16 + l15) * NF + k0 + lk;
  f32x4 acc0 = {0.f, 0.f, 0.f, 0.f};
  f32x4 acc1 = {0.f, 0.f, 0.f, 0.f};
#pragma unroll 4
  for (int kk = 0; kk < kc; kk += 32) {
    bf16x8 ah = ldb(pAh + kk);
    bf16x8 al = ldb(pAl + kk);
    bf16x8 b0 = ldb(pB0 + kk);
    bf16x8 b1 = ldb(pB1 + kk);
    acc0 = __builtin_amdgcn_mfma_f32_16x16x32_bf16(ah, b0, acc0, 0, 0, 0);
    acc0 = __builtin_amdgcn_mfma_f32_16x16x32_bf16(al, b0, acc0, 0, 0, 0);
    acc1 = __builtin_amdgcn_mfma_f32_16x16x32_bf16(ah, b1, acc1, 0, 0, 0);
    acc1 = __builtin_amdgcn_mfma_f32_16x16x32_bf16(al, b1, acc1, 0, 0, 0);
  }
  float* po = part + (size_t)blockIdx.y * 16 * NF;
#pragma unroll
  for (int r = 0; r < 4; ++r) {
    int c = (l >> 4) * 4 + r;          // D: row=(lane>>4)*4+reg -> c-dim
    po[(size_t)c * NF + nb + l15] = acc0[r];        // D col = lane&15 -> n-dim
    po[(size_t)c * NF + nb + 16 + l15] = acc1[r];
  }
}

// ---------------- hop, C=128 (layer 2): 32x32x16 MFMA ----------------
// Z planes [128][8192]; block = 128c x 128n, 4 waves (2c x 2n), wave tile 64c x 64n.
__global__ __launch_bounds__(256) void k_hop128(const unsigned short* __restrict__ S,
                                                const unsigned short* __restrict__ zhi,
                                                const unsigned short* __restrict__ zlo,
                                                float* __restrict__ part, int ktot) {
  const int kc = ktot / KSPLIT;
  const int k0 = blockIdx.y * kc;
  const int tid = threadIdx.x, l = tid & 63, w = tid >> 6;
  const int cw = w & 1, nw = w >> 1;
  const int lk = (l >> 5) * 8;
  const int l31 = l & 31;
  const int cb = cw * 64;
  const int nb = blockIdx.x * 128 + nw * 64;
  const unsigned short* pAh0 = zhi + (size_t)(cb + l31) * NF + k0 + lk;
  const unsigned short* pAh1 = zhi + (size_t)(cb + 32 + l31) * NF + k0 + lk;
  const unsigned short* pAl0 = zlo + (size_t)(cb + l31) * NF + k0 + lk;
  const unsigned short* pAl1 = zlo + (size_t)(cb + 32 + l31) * NF + k0 + lk;
  const unsigned short* pB0 = S + (size_t)(nb + l31) * NF + k0 + lk;
  const unsigned short* pB1 = S + (size_t)(nb + 32 + l31) * NF + k0 + lk;
  f32x16 acc00 = {0,0,0,0,0,0,0,0,0,0,0,0,0,0,0,0};
  f32x16 acc01 = {0,0,0,0,0,0,0,0,0,0,0,0,0,0,0,0};
  f32x16 acc10 = {0,0,0,0,0,0,0,0,0,0,0,0,0,0,0,0};
  f32x16 acc11 = {0,0,0,0,0,0,0,0,0,0,0,0,0,0,0,0};
#pragma unroll 2
  for (int kk = 0; kk < kc; kk += 16) {
    bf16x8 ah0 = ldb(pAh0 + kk);
    bf16x8 ah1 = ldb(pAh1 + kk);
    bf16x8 al0 = ldb(pAl0 + kk);
    bf16x8 al1 = ldb(pAl1 + kk);
    bf16x8 b0 = ldb(pB0 + kk);
    bf16x8 b1 = ldb(pB1 + kk);
    acc00 = __builtin_amdgcn_mfma_f32_32x32x16_bf16(ah0, b0, acc00, 0, 0, 0);
    acc00 = __builtin_amdgcn_mfma_f32_32x32x16_bf16(al0, b0, acc00, 0, 0, 0);
    acc01 = __builtin_amdgcn_mfma_f32_32x32x16_bf16(ah0, b1, acc01, 0, 0, 0);
    acc01 = __builtin_amdgcn_mfma_f32_32x32x16_bf16(al0, b1, acc01, 0, 0, 0);
    acc10 = __builtin_amdgcn_mfma_f32_32x32x16_bf16(ah1, b0, acc10, 0, 0, 0);
    acc10 = __builtin_amdgcn_mfma_f32_32x32x16_bf16(al1, b0, acc10, 0, 0, 0);
    acc11 = __builtin_amdgcn_mfma_f32_32x32x16_bf16(ah1, b1, acc11, 0, 0, 0);
    acc11 = __builtin_amdgcn_mfma_f32_32x32x16_bf16(al1, b1, acc11, 0, 0, 0);
  }
  float* po = part + (size_t)blockIdx.y * 128 * NF;
#pragma unroll
  for (int r = 0; r < 16; ++r) {
    int cr = (r & 3) + 8 * (r >> 2) + 4 * (l >> 5);   // D row pattern -> c-dim
    po[(size_t)(cb + cr) * NF + nb + l31] = acc00[r];
    po[(size_t)(cb + cr) * NF + nb + 32 + l31] = acc01[r];
    po[(size_t)(cb + 32 + cr) * NF + nb + l31] = acc10[r];
    po[(size_t)(cb + 32 + cr) * NF + nb + 32 + l31] = acc11[r];
  }
}

// ---------------- finalize: sum KSPLIT partials -> z f32 (+ hi/lo bf16 planes) ----------------
__global__ void k_fin(const float* __restrict__ part, float* __restrict__ zf,
                      unsigned short* __restrict__ hi, unsigned short* __restrict__ lo,
                      int total4, int writeHL) {
  int i = blockIdx.x * blockDim.x + threadIdx.x;
  int stride = gridDim.x * blockDim.x;
  for (; i < total4; i += stride) {
    float4 v = reinterpret_cast<const float4*>(part)[i];
#pragma unroll
    for (int s = 1; s < KSPLIT; ++s) {
      float4 u = reinterpret_cast<const float4*>(part)[(size_t)s * total4 + i];
      v.x += u.x; v.y += u.y; v.z += u.z; v.w += u.w;
    }
    reinterpret_cast<float4*>(zf)[i] = v;
    if (writeHL) {
      ushort4 h, lw;
      h.x = f2bf(v.x); lw.x = f2bf(v.x - bf2f(h.x));
      h.y = f2bf(v.y); lw.y = f2bf(v.y - bf2f(h.y));
      h.z = f2bf(v.z); lw.z = f2bf(v.z - bf2f(h.z));
      h.w = f2bf(v.w); lw.w = f2bf(v.w - bf2f(h.w));
      reinterpret_cast<ushort4*>(hi)[i] = h;
      reinterpret_cast<ushort4*>(lo)[i] = lw;
    }
  }
}

// ---------------- layer-1 tap combine + relu: y1[c=b*8+g][n] ----------------
__global__ void k_comb1(const float* __restrict__ x, const float* __restrict__ z1,
                        const float* __restrict__ z2, const float* __restrict__ z3,
                        const float* __restrict__ h1, const float* __restrict__ bf1,
                        float* __restrict__ y1) {
  int n = blockIdx.x * 256 + threadIdx.x;
  int c = blockIdx.y;            // b*8+g
  int b = c >> 3, g = c & 7;
  size_t zo = (size_t)b * NF + n;
  float v = bf1[g] + h1[g * 4 + 0] * x[zo] + h1[g * 4 + 1] * z1[zo] +
            h1[g * 4 + 2] * z2[zo] + h1[g * 4 + 3] * z3[zo];
  y1[(size_t)c * NF + n] = fmaxf(v, 0.f);
}

// ---------------- pool 1: max over nbh1, emit pooled f32 [128][2048] + hi/lo planes [128][8192] ----------------
__global__ void k_pool1(const float* __restrict__ y1, const int* __restrict__ nbh,
                        float* __restrict__ pooled, unsigned short* __restrict__ hi,
                        unsigned short* __restrict__ lo) {
  int n1 = blockIdx.x * 256 + threadIdx.x;   // < 2048
  int c = blockIdx.y;                        // b*8+f
  const float* row = y1 + (size_t)c * NF;
  float m = -1e30f;
#pragma unroll
  for (int j = 0; j < 16; ++j) m = fmaxf(m, row[nbh[n1 * 16 + j]]);
  pooled[(size_t)c * 2048 + n1] = m;
  unsigned short h = f2bf(m);
  hi[(size_t)c * NF + n1] = h;
  lo[(size_t)c * NF + n1] = f2bf(m - bf2f(h));
}

// ---------------- layer-2 tap combine + relu: y2[c=b*16+g][n], n < 2048 ----------------
__global__ void k_comb2(const float* __restrict__ z0, const float* __restrict__ z1,
                        const float* __restrict__ z2, const float* __restrict__ z3,
                        const float* __restrict__ h2, const float* __restrict__ bf2,
                        float* __restrict__ y2) {
  int n = blockIdx.x * 256 + threadIdx.x;    // < 2048
  int c = blockIdx.y;                        // b*16+g
  int b = c >> 4, g = c & 15;
  float acc = bf2[g];
#pragma unroll
  for (int f = 0; f < 8; ++f) {
    size_t ro = (size_t)(b * 8 + f);
    float v0 = z0[ro * 2048 + n];            // pooled pitch 2048
    float v1 = z1[ro * NF + n];
    float v2 = z2[ro * NF + n];
    float v3 = z3[ro * NF + n];
    acc += h2[(g * 4 + 0) * 8 + f] * v0 + h2[(g * 4 + 1) * 8 + f] * v1 +
           h2[(g * 4 + 2) * 8 + f] * v2 + h2[(g * 4 + 3) * 8 + f] * v3;
  }
  y2[(size_t)c * 2048 + n] = fmaxf(acc, 0.f);
}

// ---------------- pool 2: [256][512] ----------------
__global__ void k_pool2(const float* __restrict__ y2, const int* __restrict__ nbh,
                        float* __restrict__ pooled) {
  int n2 = blockIdx.x * 256 + threadIdx.x;   // < 512
  int c = blockIdx.y;                        // b*16+g
  const float* row = y2 + (size_t)c * 2048;
  float m = -1e30f;
#pragma unroll
  for (int j = 0; j < 16; ++j) m = fmaxf(m, row[nbh[n2 * 16 + j]]);
  pooled[(size_t)c * 512 + n2] = m;
}

// ---------------- MLP layer 1 (split-K over 64 chunks, atomic accumulate) ----------------
__global__ __launch_bounds__(256) void k_mlp1(const float* __restrict__ p2,
                                              const float* __restrict__ W1,
                                              float* __restrict__ hid) {
  __shared__ float fs[128][16];
  int kc0 = blockIdx.x * 128;
  int tid = threadIdx.x;
#pragma unroll
  for (int r = 0; r < 8; ++r) {
    int idx = tid + r * 256;                 // 0..2047
    int i = idx >> 4, b = idx & 15;
    int k = kc0 + i;
    int g = k >> 9, n2 = k & 511;
    fs[i][b] = p2[(size_t)(b * 16 + g) * 512 + n2];
  }
  __syncthreads();
  float facc[16];
#pragma unroll
  for (int b = 0; b < 16; ++b) facc[b] = 0.f;
  for (int i = 0; i < 128; ++i) {
    float wv = W1[(size_t)(kc0 + i) * 256 + tid];
#pragma unroll
    for (int b = 0; b < 16; ++b) facc[b] += fs[i][b] * wv;
  }
#pragma unroll
  for (int b = 0; b < 16; ++b) atomicAdd(&hid[b * 256 + tid], facc[b]);
}

// ---------------- MLP layer 2 (bias+relu on hid, then x W2 + bm2) ----------------
__global__ __launch_bounds__(1024) void k_mlp2(const float* __restrict__ hid,
                                               const float* __restrict__ bm1,
                                               const float* __restrict__ W2,
                                               const float* __restrict__ bm2,
                                               float* __restrict__ out) {
  int t = threadIdx.x;
  int o = t & 63, b = t >> 6;
  float acc = bm2[o];
  for (int h = 0; h < 256; ++h) {
    float hv = fmaxf(hid[b * 256 + h] + bm1[h], 0.f);
    acc += hv * W2[h * 64 + o];
  }
  out[b * 64 + o] = acc;
}

extern "C" void kernel_launch(void* const* d_in, const int* in_sizes, int n_in,
                              void* d_out, int out_size, void* d_ws, size_t ws_size,
                              hipStream_t stream) {
  const float* x   = (const float*)d_in[0];
  const float* S   = (const float*)d_in[1];
  const float* h1  = (const float*)d_in[2];
  const float* bf1 = (const float*)d_in[3];
  const float* h2  = (const float*)d_in[4];
  const float* bf2 = (const float*)d_in[5];
  const float* W1  = (const float*)d_in[6];
  const float* bm1 = (const float*)d_in[7];
  const float* W2  = (const float*)d_in[8];
  const float* bm2 = (const float*)d_in[9];
  const int* nbh1  = (const int*)d_in[10];
  const int* nbh2  = (const int*)d_in[11];
  float* out = (float*)d_out;

  char* ws = (char*)d_ws;
  size_t off = 0;
  auto alloc = [&](size_t bytes) -> char* {
    char* p = ws + off;
    off += (bytes + 255) & ~(size_t)255;
    return p;
  };
  unsigned short* Sb = (unsigned short*)alloc((size_t)NF * NF * 2);          // 128 MB
  float* part = (float*)alloc((size_t)KSPLIT * 128 * NF * 4);                // 32 MB
  float* zf_l2[3];
  for (int i = 0; i < 3; ++i) zf_l2[i] = (float*)alloc((size_t)128 * NF * 4);
  unsigned short *zhi_l2[3], *zlo_l2[3];
  for (int i = 0; i < 3; ++i) {
    zhi_l2[i] = (unsigned short*)alloc((size_t)128 * NF * 2);
    zlo_l2[i] = (unsigned short*)alloc((size_t)128 * NF * 2);
  }
  float* zf_l1[3];
  for (int i = 0; i < 3; ++i) zf_l1[i] = (float*)alloc((size_t)16 * NF * 4);
  unsigned short *zhi_l1[3], *zlo_l1[3];
  for (int i = 0; i < 3; ++i) {
    zhi_l1[i] = (unsigned short*)alloc((size_t)16 * NF * 2);
    zlo_l1[i] = (unsigned short*)alloc((size_t)16 * NF * 2);
  }
  float* y1 = (float*)alloc((size_t)128 * NF * 4);
  float* pooledY1 = (float*)alloc((size_t)128 * 2048 * 4);
  float* y2 = (float*)alloc((size_t)256 * 2048 * 4);
  float* pooled2 = (float*)alloc((size_t)256 * 512 * 4);
  float* hid = (float*)alloc((size_t)16 * 256 * 4);

  // 1. S -> bf16 (reused by all 6 hops; fits Infinity Cache)
  k_cvt<<<4096, 256, 0, stream>>>(S, Sb, NF * NF / 4);
  // 2. layer-1 z0 = x split into hi/lo planes [16][8192]
  k_split<<<512, 256, 0, stream>>>(x, zhi_l1[0], zlo_l1[0], 16 * NF);
  // 3. layer-1 hops (K = 8192)
  for (int k = 0; k < 3; ++k) {
    k_hop16<<<dim3(64, KSPLIT), 256, 0, stream>>>(Sb, zhi_l1[k], zlo_l1[k], part, NF);
    int wh = (k < 2);
    k_fin<<<128, 256, 0, stream>>>(part, zf_l1[k], wh ? zhi_l1[k + 1] : zhi_l1[0],
                                   wh ? zlo_l1[k + 1] : zlo_l1[0], 16 * NF / 4, wh);
  }
  // 4. combine + relu -> y1 [128][8192]
  k_comb1<<<dim3(32, 128), 256, 0, stream>>>(x, zf_l1[0], zf_l1[1], zf_l1[2], h1, bf1, y1);
  // 5. pool 1 -> pooled f32 [128][2048] + layer-2 z0 hi/lo planes
  k_pool1<<<dim3(8, 128), 256, 0, stream>>>(y1, nbh1, pooledY1, zhi_l2[0], zlo_l2[0]);
  // 6. layer-2 hops (hop 0 has only K=2048 valid input rows)
  for (int k = 0; k < 3; ++k) {
    k_hop128<<<dim3(64, KSPLIT), 256, 0, stream>>>(Sb, zhi_l2[k], zlo_l2[k], part,
                                                   k == 0 ? 2048 : NF);
    int wh = (k < 2);
    k_fin<<<1024, 256, 0, stream>>>(part, zf_l2[k], wh ? zhi_l2[k + 1] : zhi_l2[0],
                                    wh ? zlo_l2[k + 1] : zlo_l2[0], 128 * NF / 4, wh);
  }
  // 7. combine + relu -> y2 [256][2048]
  k_comb2<<<dim3(8, 256), 256, 0, stream>>>(pooledY1, zf_l2[0], zf_l2[1], zf_l2[2], h2, bf2, y2);
  // 8. pool 2 -> pooled2 [256][512]
  k_pool2<<<dim3(2, 256), 256, 0, stream>>>(y2, nbh2, pooled2);
  // 9. MLP
  hipMemsetAsync(hid, 0, 16 * 256 * 4, stream);
  k_mlp1<<<64, 256, 0, stream>>>(pooled2, W1, hid);
  k_mlp2<<<1, 1024, 0, stream>>>(hid, bm1, W2, bm2, out);
}

// Round 2
// 653.377 us; speedup vs baseline: 1.2833x; 1.2833x over previous
//
#include <hip/hip_runtime.h>
#include <hip/hip_bf16.h>

typedef _Float16 f16x8 __attribute__((ext_vector_type(8)));
typedef _Float16 f16x4 __attribute__((ext_vector_type(4)));
typedef float f32x4 __attribute__((ext_vector_type(4)));

#define NF 8192

static __device__ __forceinline__ void gload_lds16(const _Float16* g, _Float16* l) {
  __builtin_amdgcn_global_load_lds(
      (const __attribute__((address_space(1))) void*)g,
      (__attribute__((address_space(3))) void*)l, 16, 0, 0);
}

// ---------------- x -> f16 plane (layer-1 z0, [16][8192]) ----------------
__global__ void k_split(const float* __restrict__ x, _Float16* __restrict__ d, int n4) {
  int i = blockIdx.x * blockDim.x + threadIdx.x;
  if (i < n4) {
    f32x4 v = reinterpret_cast<const f32x4*>(x)[i];
    f16x4 o;
    o[0] = (_Float16)v[0]; o[1] = (_Float16)v[1];
    o[2] = (_Float16)v[2]; o[3] = (_Float16)v[3];
    reinterpret_cast<f16x4*>(d)[i] = o;
  }
}

// ---------------- hop, C=16 (layer 1), streaming, no LDS ----------------
// part[by][c][n] = sum_k z[c][m] * S[n][m]. CVT=1: read f32 S, emit f16 S.
template <int CVT>
__global__ __launch_bounds__(256) void k_hop16(const float* __restrict__ Sf,
                                               const _Float16* __restrict__ S16,
                                               _Float16* __restrict__ S16w,
                                               const _Float16* __restrict__ z,
                                               float* __restrict__ part, int ksplit) {
  const int kc = NF / ksplit;
  const int k0 = blockIdx.y * kc;
  const int tid = threadIdx.x, l = tid & 63, w = tid >> 6;
  const int l15 = l & 15;
  const int lk = (l >> 4) * 8;
  const int nb = blockIdx.x * 256 + w * 64;
  const _Float16* pA = z + (size_t)l15 * NF + k0 + lk;
  size_t rowoff[4];
#pragma unroll
  for (int n = 0; n < 4; ++n) rowoff[n] = (size_t)(nb + n * 16 + l15) * NF + k0 + lk;
  f32x4 acc[4];
#pragma unroll
  for (int n = 0; n < 4; ++n) acc[n] = (f32x4){0.f, 0.f, 0.f, 0.f};
#pragma unroll 2
  for (int kk = 0; kk < kc; kk += 32) {
    f16x8 a = *reinterpret_cast<const f16x8*>(pA + kk);
#pragma unroll
    for (int n = 0; n < 4; ++n) {
      f16x8 b;
      if (CVT) {
        f32x4 u0 = *reinterpret_cast<const f32x4*>(Sf + rowoff[n] + kk);
        f32x4 u1 = *reinterpret_cast<const f32x4*>(Sf + rowoff[n] + kk + 4);
#pragma unroll
        for (int j = 0; j < 4; ++j) { b[j] = (_Float16)u0[j]; b[4 + j] = (_Float16)u1[j]; }
        *reinterpret_cast<f16x8*>(S16w + rowoff[n] + kk) = b;
      } else {
        b = *reinterpret_cast<const f16x8*>(S16 + rowoff[n] + kk);
      }
      acc[n] = __builtin_amdgcn_mfma_f32_16x16x32_f16(a, b, acc[n], 0, 0, 0);
    }
  }
  float* po = part + (size_t)blockIdx.y * 16 * NF;
#pragma unroll
  for (int n = 0; n < 4; ++n)
#pragma unroll
    for (int r = 0; r < 4; ++r)
      po[(size_t)((l >> 4) * 4 + r) * NF + nb + n * 16 + l15] = acc[n][r];
}

// ---------------- hop, C=128 (layer 2): m97-style LDS GEMM ----------------
// Block tile 128c x 128n, BK=32, 4 waves (2c x 2n), wave 64x64 as 4x4 frags of 16x16x32.
// LDS rows of 32 f16 (64 B), XOR swizzle byte ^= ((row&3)<<4); staging via
// global_load_lds with inverse-swizzled per-lane global source (linear LDS dest).
__global__ __launch_bounds__(256) void k_hop128(const _Float16* __restrict__ S16,
                                                const _Float16* __restrict__ z,
                                                float* __restrict__ part,
                                                int ktot, int ksplit, int np) {
  __shared__ _Float16 lA[4096];   // 128 rows x 32 f16
  __shared__ _Float16 lB[4096];
  const int kc = ktot / ksplit;
  const int k0 = blockIdx.y * kc;
  const int tid = threadIdx.x, l = tid & 63, w = tid >> 6;
  const int cw = w & 1, nw = w >> 1;
  const int l15 = l & 15;
  const int nb = blockIdx.x * 128;
  // staging source (round 0: t=tid, round 1: t=tid+256)
  const int t0 = tid, t1 = tid + 256;
  const int r0row = t0 >> 2, r1row = t1 >> 2;
  const int r0k = (((t0 & 3) * 16) ^ ((r0row & 3) << 4)) >> 1;  // halfword offset
  const int r1k = (((t1 & 3) * 16) ^ ((r1row & 3) << 4)) >> 1;
  const _Float16* sA0 = z + (size_t)r0row * NF + k0 + r0k;
  const _Float16* sA1 = z + (size_t)r1row * NF + k0 + r1k;
  const _Float16* sB0 = S16 + (size_t)(nb + r0row) * NF + k0 + r0k;
  const _Float16* sB1 = S16 + (size_t)(nb + r1row) * NF + k0 + r1k;
  _Float16* dA0 = lA + w * 512;
  _Float16* dA1 = lA + 2048 + w * 512;
  _Float16* dB0 = lB + w * 512;
  _Float16* dB1 = lB + 2048 + w * 512;
  // fragment read offsets (halfwords)
  int aoff[4], boff[4];
#pragma unroll
  for (int m = 0; m < 4; ++m) {
    int row = cw * 64 + m * 16 + l15;
    aoff[m] = row * 32 + (((((l >> 4) * 16)) ^ ((row & 3) << 4)) >> 1);
    row = nw * 64 + m * 16 + l15;
    boff[m] = row * 32 + (((((l >> 4) * 16)) ^ ((row & 3) << 4)) >> 1);
  }
  f32x4 acc[4][4];
#pragma unroll
  for (int m = 0; m < 4; ++m)
#pragma unroll
    for (int n = 0; n < 4; ++n) acc[m][n] = (f32x4){0.f, 0.f, 0.f, 0.f};
  const int nsteps = kc >> 5;
  for (int s = 0; s < nsteps; ++s) {
    const int ko = s * 32;
    gload_lds16(sA0 + ko, dA0);
    gload_lds16(sA1 + ko, dA1);
    gload_lds16(sB0 + ko, dB0);
    gload_lds16(sB1 + ko, dB1);
    __syncthreads();
    f16x8 a[4], b[4];
#pragma unroll
    for (int m = 0; m < 4; ++m) a[m] = *reinterpret_cast<const f16x8*>(lA + aoff[m]);
#pragma unroll
    for (int n = 0; n < 4; ++n) b[n] = *reinterpret_cast<const f16x8*>(lB + boff[n]);
#pragma unroll
    for (int m = 0; m < 4; ++m)
#pragma unroll
      for (int n = 0; n < 4; ++n)
        acc[m][n] = __builtin_amdgcn_mfma_f32_16x16x32_f16(a[m], b[n], acc[m][n], 0, 0, 0);
    __syncthreads();
  }
  float* po = part + (size_t)blockIdx.y * 128 * np;
#pragma unroll
  for (int m = 0; m < 4; ++m) {
    int c = cw * 64 + m * 16 + (l >> 4) * 4;
#pragma unroll
    for (int n = 0; n < 4; ++n) {
      int col = nb + nw * 64 + n * 16 + l15;
#pragma unroll
      for (int r = 0; r < 4; ++r) po[(size_t)(c + r) * np + col] = acc[m][n][r];
    }
  }
}

// ---------------- finalize: sum nsplit partials -> f16 plane ----------------
__global__ void k_fin(const float* __restrict__ part, _Float16* __restrict__ out,
                      int nsplit, int total4) {
  int i = blockIdx.x * blockDim.x + threadIdx.x;
  int stride = gridDim.x * blockDim.x;
  for (; i < total4; i += stride) {
    f32x4 v = reinterpret_cast<const f32x4*>(part)[i];
    for (int s = 1; s < nsplit; ++s) {
      f32x4 u = reinterpret_cast<const f32x4*>(part)[(size_t)s * total4 + i];
      v[0] += u[0]; v[1] += u[1]; v[2] += u[2]; v[3] += u[3];
    }
    f16x4 o;
    o[0] = (_Float16)v[0]; o[1] = (_Float16)v[1];
    o[2] = (_Float16)v[2]; o[3] = (_Float16)v[3];
    reinterpret_cast<f16x4*>(out)[i] = o;
  }
}

// ---------------- layer-1 tap combine + relu -> y1 f32 [128][8192] ----------------
__global__ void k_comb1(const _Float16* __restrict__ z0, const _Float16* __restrict__ z1,
                        const _Float16* __restrict__ z2, const _Float16* __restrict__ z3,
                        const float* __restrict__ h1, const float* __restrict__ bf1,
                        float* __restrict__ y1) {
  int i = blockIdx.x * 256 + threadIdx.x;      // n/4 index, < 2048
  int c = blockIdx.y;                          // b*8+g
  int b = c >> 3, g = c & 7;
  size_t ro = (size_t)b * (NF / 4);
  f16x4 v0 = reinterpret_cast<const f16x4*>(z0)[ro + i];
  f16x4 v1 = reinterpret_cast<const f16x4*>(z1)[ro + i];
  f16x4 v2 = reinterpret_cast<const f16x4*>(z2)[ro + i];
  f16x4 v3 = reinterpret_cast<const f16x4*>(z3)[ro + i];
  float h0 = h1[g * 4 + 0], hh1 = h1[g * 4 + 1], h2v = h1[g * 4 + 2], h3 = h1[g * 4 + 3];
  float bb = bf1[g];
  f32x4 o;
#pragma unroll
  for (int j = 0; j < 4; ++j)
    o[j] = fmaxf(bb + h0 * (float)v0[j] + hh1 * (float)v1[j] + h2v * (float)v2[j] + h3 * (float)v3[j], 0.f);
  reinterpret_cast<f32x4*>(y1)[(size_t)c * (NF / 4) + i] = o;
}

// ---------------- pool 1 -> layer-2 z0 f16 plane [128][8192] (cols<2048) ----------------
__global__ void k_pool1(const float* __restrict__ y1, const int* __restrict__ nbh,
                        _Float16* __restrict__ z0l2) {
  int n1 = blockIdx.x * 256 + threadIdx.x;   // < 2048
  int c = blockIdx.y;                        // b*8+f
  const float* row = y1 + (size_t)c * NF;
  float m = -1e30f;
#pragma unroll
  for (int j = 0; j < 16; ++j) m = fmaxf(m, row[nbh[n1 * 16 + j]]);
  z0l2[(size_t)c * NF + n1] = (_Float16)m;
}

// ---------------- layer-2 tap combine + relu -> y2 f32 [256][2048] ----------------
__global__ void k_comb2(const _Float16* __restrict__ z0, const _Float16* __restrict__ z1,
                        const _Float16* __restrict__ z2, const _Float16* __restrict__ z3,
                        const float* __restrict__ h2, const float* __restrict__ bf2,
                        float* __restrict__ y2) {
  int i = blockIdx.x * 256 + threadIdx.x;    // n/4 index, < 512
  int c = blockIdx.y;                        // b*16+g
  int b = c >> 4, g = c & 15;
  f32x4 acc;
  float bb = bf2[g];
#pragma unroll
  for (int j = 0; j < 4; ++j) acc[j] = bb;
#pragma unroll
  for (int f = 0; f < 8; ++f) {
    size_t rb = (size_t)(b * 8 + f);
    f16x4 t0 = reinterpret_cast<const f16x4*>(z0)[rb * (NF / 4) + i];
    f16x4 t1 = reinterpret_cast<const f16x4*>(z1)[rb * (NF / 4) + i];
    f16x4 t2 = reinterpret_cast<const f16x4*>(z2)[rb * (NF / 4) + i];
    f16x4 t3 = reinterpret_cast<const f16x4*>(z3)[rb * 512 + i];
    float w0 = h2[(g * 4 + 0) * 8 + f], w1 = h2[(g * 4 + 1) * 8 + f];
    float w2 = h2[(g * 4 + 2) * 8 + f], w3 = h2[(g * 4 + 3) * 8 + f];
#pragma unroll
    for (int j = 0; j < 4; ++j)
      acc[j] += w0 * (float)t0[j] + w1 * (float)t1[j] + w2 * (float)t2[j] + w3 * (float)t3[j];
  }
#pragma unroll
  for (int j = 0; j < 4; ++j) acc[j] = fmaxf(acc[j], 0.f);
  reinterpret_cast<f32x4*>(y2)[(size_t)c * 512 + i] = acc;
}

// ---------------- pool 2 -> pooled2 f32 [256][512] ----------------
__global__ void k_pool2(const float* __restrict__ y2, const int* __restrict__ nbh,
                        float* __restrict__ pooled) {
  int n2 = blockIdx.x * 256 + threadIdx.x;   // < 512
  int c = blockIdx.y;                        // b*16+g
  const float* row = y2 + (size_t)c * 2048;
  float m = -1e30f;
#pragma unroll
  for (int j = 0; j < 16; ++j) m = fmaxf(m, row[nbh[n2 * 16 + j]]);
  pooled[(size_t)c * 512 + n2] = m;
}

// ---------------- MLP layer 1 (split-K, atomic accumulate) ----------------
__global__ __launch_bounds__(256) void k_mlp1(const float* __restrict__ p2,
                                              const float* __restrict__ W1,
                                              float* __restrict__ hid) {
  __shared__ float fs[128][16];
  int kc0 = blockIdx.x * 128;
  int tid = threadIdx.x;
#pragma unroll
  for (int r = 0; r < 8; ++r) {
    int idx = tid + r * 256;                 // 0..2047
    int i = idx >> 4, b = idx & 15;
    int k = kc0 + i;
    int g = k >> 9, n2 = k & 511;
    fs[i][b] = p2[(size_t)(b * 16 + g) * 512 + n2];
  }
  __syncthreads();
  float facc[16];
#pragma unroll
  for (int b = 0; b < 16; ++b) facc[b] = 0.f;
  for (int i = 0; i < 128; ++i) {
    float wv = W1[(size_t)(kc0 + i) * 256 + tid];
#pragma unroll
    for (int b = 0; b < 16; ++b) facc[b] += fs[i][b] * wv;
  }
#pragma unroll
  for (int b = 0; b < 16; ++b) atomicAdd(&hid[b * 256 + tid], facc[b]);
}

// ---------------- MLP layer 2 ----------------
__global__ __launch_bounds__(1024) void k_mlp2(const float* __restrict__ hid,
                                               const float* __restrict__ bm1,
                                               const float* __restrict__ W2,
                                               const float* __restrict__ bm2,
                                               float* __restrict__ out) {
  int t = threadIdx.x;
  int o = t & 63, b = t >> 6;
  float acc = bm2[o];
  for (int h = 0; h < 256; ++h) {
    float hv = fmaxf(hid[b * 256 + h] + bm1[h], 0.f);
    acc += hv * W2[h * 64 + o];
  }
  out[b * 64 + o] = acc;
}

extern "C" void kernel_launch(void* const* d_in, const int* in_sizes, int n_in,
                              void* d_out, int out_size, void* d_ws, size_t ws_size,
                              hipStream_t stream) {
  const float* x   = (const float*)d_in[0];
  const float* S   = (const float*)d_in[1];
  const float* h1  = (const float*)d_in[2];
  const float* bf1 = (const float*)d_in[3];
  const float* h2  = (const float*)d_in[4];
  const float* bf2 = (const float*)d_in[5];
  const float* W1  = (const float*)d_in[6];
  const float* bm1 = (const float*)d_in[7];
  const float* W2  = (const float*)d_in[8];
  const float* bm2 = (const float*)d_in[9];
  const int* nbh1  = (const int*)d_in[10];
  const int* nbh2  = (const int*)d_in[11];
  float* out = (float*)d_out;

  char* ws = (char*)d_ws;
  size_t off = 0;
  auto alloc = [&](size_t bytes) -> char* {
    char* p = ws + off;
    off += (bytes + 255) & ~(size_t)255;
    return p;
  };
  _Float16* S16 = (_Float16*)alloc((size_t)NF * NF * 2);            // 128 MB
  float* part = (float*)alloc((size_t)8 * 128 * NF * 4);            // 32 MB
  _Float16* zl1[4];
  for (int i = 0; i < 4; ++i) zl1[i] = (_Float16*)alloc((size_t)16 * NF * 2);
  _Float16* zl2[4];
  for (int i = 0; i < 3; ++i) zl2[i] = (_Float16*)alloc((size_t)128 * NF * 2);
  zl2[3] = (_Float16*)alloc((size_t)128 * 2048 * 2);
  float* y1 = (float*)alloc((size_t)128 * NF * 4);
  float* y2 = (float*)alloc((size_t)256 * 2048 * 4);
  float* pooled2 = (float*)alloc((size_t)256 * 512 * 4);
  float* hid = (float*)alloc((size_t)16 * 256 * 4);

  // layer-1 z0 = x as f16 plane
  k_split<<<128, 256, 0, stream>>>(x, zl1[0], 16 * NF / 4);
  // layer-1 hops (hop 0 also converts S f32 -> f16)
  k_hop16<1><<<dim3(32, 16), 256, 0, stream>>>(S, S16, S16, zl1[0], part, 16);
  k_fin<<<128, 256, 0, stream>>>(part, zl1[1], 16, 16 * NF / 4);
  k_hop16<0><<<dim3(32, 16), 256, 0, stream>>>(S, S16, S16, zl1[1], part, 16);
  k_fin<<<128, 256, 0, stream>>>(part, zl1[2], 16, 16 * NF / 4);
  k_hop16<0><<<dim3(32, 16), 256, 0, stream>>>(S, S16, S16, zl1[2], part, 16);
  k_fin<<<128, 256, 0, stream>>>(part, zl1[3], 16, 16 * NF / 4);
  // combine + relu -> y1, pool -> layer-2 z0 plane
  k_comb1<<<dim3(8, 128), 256, 0, stream>>>(zl1[0], zl1[1], zl1[2], zl1[3], h1, bf1, y1);
  k_pool1<<<dim3(8, 128), 256, 0, stream>>>(y1, nbh1, zl2[0]);
  // layer-2 hops
  k_hop128<<<dim3(64, 8), 256, 0, stream>>>(S16, zl2[0], part, 2048, 8, NF);   // K=2048
  k_fin<<<512, 256, 0, stream>>>(part, zl2[1], 8, 128 * NF / 4);
  k_hop128<<<dim3(64, 8), 256, 0, stream>>>(S16, zl2[1], part, NF, 8, NF);     // full
  k_fin<<<512, 256, 0, stream>>>(part, zl2[2], 8, 128 * NF / 4);
  k_hop128<<<dim3(16, 16), 256, 0, stream>>>(S16, zl2[2], part, NF, 16, 2048); // rows<2048
  k_fin<<<256, 256, 0, stream>>>(part, zl2[3], 16, 128 * 2048 / 4);
  // combine + relu -> y2, pool 2
  k_comb2<<<dim3(2, 256), 256, 0, stream>>>(zl2[0], zl2[1], zl2[2], zl2[3], h2, bf2, y2);
  k_pool2<<<dim3(2, 256), 256, 0, stream>>>(y2, nbh2, pooled2);
  // MLP
  hipMemsetAsync(hid, 0, 16 * 256 * 4, stream);
  k_mlp1<<<64, 256, 0, stream>>>(pooled2, W1, hid);
  k_mlp2<<<1, 1024, 0, stream>>>(hid, bm1, W2, bm2, out);
}